// Round 1
// baseline (3049.156 us; speedup 1.0000x reference)
//
#include <hip/hip_runtime.h>
#include <hip/hip_bf16.h>

#define H_     32
#define D_     128
#define HID_   4096
#define DOFF_  1024
#define BD_    32
#define T_     1056
#define MAXKV_ 513
#define R_     16
#define NA_    4
#define SCALE_ 0.08838834764831845f  /* 1/sqrt(128) */

// ---------------------------------------------------------------------------
// u[t][r] = x[t] . WA[aid(t)][:,r]   (LoRA down-projection, per-token adapter)
// ---------------------------------------------------------------------------
__global__ __launch_bounds__(256) void lora_u_kernel(
    const float* __restrict__ X, const float* __restrict__ WA,
    const int* __restrict__ segment, float* __restrict__ U) {
  int t = blockIdx.x;
  int tid = threadIdx.x;

  int aid = 0;
#pragma unroll
  for (int i = 1; i <= NA_; ++i)
    if (t >= segment[i]) aid = i;
  if (aid > NA_ - 1) aid = NA_ - 1;

  const float* x = X + (size_t)t * HID_;
  const float* wa = WA + (size_t)aid * HID_ * R_;

  float part[R_];
#pragma unroll
  for (int r = 0; r < R_; ++r) part[r] = 0.f;

  for (int h = tid; h < HID_; h += 256) {
    float xv = x[h];
    const float* w = wa + (size_t)h * R_;
#pragma unroll
    for (int r = 0; r < R_; ++r) part[r] += xv * w[r];
  }

  __shared__ float red[256][R_ + 1];
#pragma unroll
  for (int r = 0; r < R_; ++r) red[tid][r] = part[r];
  __syncthreads();
  for (int s = 128; s > 0; s >>= 1) {
    if (tid < s) {
#pragma unroll
      for (int r = 0; r < R_; ++r) red[tid][r] += red[tid + s][r];
    }
    __syncthreads();
  }
  if (tid < R_) U[(size_t)t * R_ + tid] = red[0][tid];
}

// ---------------------------------------------------------------------------
// Y[t][n] = X[t] . W[:,n] + sum_r U[t][r] * BMAT[aid(t)][r][n]
// 64x64 tile, BK=16, 256 threads, 4x4 per thread, fp32.
// ---------------------------------------------------------------------------
#define BM 64
#define BN 64
#define BK 16

__global__ __launch_bounds__(256) void gemm_lora_kernel(
    const float* __restrict__ X, const float* __restrict__ W,
    const float* __restrict__ U, const float* __restrict__ BMAT,
    const int* __restrict__ segment, float* __restrict__ Y, int Trows) {
  __shared__ float As[BK][BM];   // As[k][m]
  __shared__ float Bs[BK][BN];   // Bs[k][n]

  int tid = threadIdx.x;
  int tx = tid & 15, ty = tid >> 4;
  int m0 = blockIdx.y * BM, n0 = blockIdx.x * BN;

  float c[4][4];
#pragma unroll
  for (int i = 0; i < 4; ++i)
#pragma unroll
    for (int j = 0; j < 4; ++j) c[i][j] = 0.f;

  int arow = tid >> 2, aquad = tid & 3;   // A loader: 64 rows x 4 quads
  int brow = tid >> 4, bquad = tid & 15;  // B loader: 16 k-rows x 16 quads

  for (int k0 = 0; k0 < HID_; k0 += BK) {
    float4 av = make_float4(0.f, 0.f, 0.f, 0.f);
    int ta = m0 + arow;
    if (ta < Trows)
      av = *(const float4*)(X + (size_t)ta * HID_ + k0 + aquad * 4);
    float4 bv = *(const float4*)(W + (size_t)(k0 + brow) * HID_ + n0 + bquad * 4);

    __syncthreads();  // previous iteration's reads done before overwrite
    As[aquad * 4 + 0][arow] = av.x;
    As[aquad * 4 + 1][arow] = av.y;
    As[aquad * 4 + 2][arow] = av.z;
    As[aquad * 4 + 3][arow] = av.w;
    *(float4*)&Bs[brow][bquad * 4] = bv;
    __syncthreads();

#pragma unroll
    for (int k = 0; k < BK; ++k) {
      float a[4], b[4];
#pragma unroll
      for (int i = 0; i < 4; ++i) a[i] = As[k][ty * 4 + i];
#pragma unroll
      for (int j = 0; j < 4; ++j) b[j] = Bs[k][tx * 4 + j];
#pragma unroll
      for (int i = 0; i < 4; ++i)
#pragma unroll
        for (int j = 0; j < 4; ++j) c[i][j] += a[i] * b[j];
    }
  }

  // epilogue: add segmented LoRA up-projection, store
#pragma unroll
  for (int i = 0; i < 4; ++i) {
    int t = m0 + ty * 4 + i;
    if (t >= Trows) continue;
    int aid = 0;
#pragma unroll
    for (int s = 1; s <= NA_; ++s)
      if (t >= segment[s]) aid = s;
    if (aid > NA_ - 1) aid = NA_ - 1;

    const float* bbase = BMAT + (size_t)aid * R_ * HID_ + n0;
    float acc[4];
#pragma unroll
    for (int j = 0; j < 4; ++j) acc[j] = c[i][j];
#pragma unroll
    for (int r = 0; r < R_; ++r) {
      float ur = U[(size_t)t * R_ + r];
      const float* bm = bbase + (size_t)r * HID_;
#pragma unroll
      for (int j = 0; j < 4; ++j) acc[j] += ur * bm[tx * 4 + j];
    }
#pragma unroll
    for (int j = 0; j < 4; ++j)
      Y[(size_t)t * HID_ + n0 + tx * 4 + j] = acc[j];
  }
}

// ---------------------------------------------------------------------------
// Ragged causal prefill attention. One wave per (head, query).
// Lanes split D=128 into 2 elems/lane; per-key dot via shfl_xor reduction.
// ---------------------------------------------------------------------------
__global__ __launch_bounds__(256) void attn_prefill_kernel(
    const float* __restrict__ qp, const float* __restrict__ kp,
    const float* __restrict__ vp, const int* __restrict__ indptr,
    float* __restrict__ attn) {
  int h = blockIdx.y;
  int wave = threadIdx.x >> 6;
  int lane = threadIdx.x & 63;
  int q = blockIdx.x * 4 + wave;   // grid.x = DOFF_/4

  int seg_start = 0;
#pragma unroll
  for (int i = 1; i <= NA_; ++i)
    if (q >= indptr[i]) seg_start = indptr[i];

  const float* qptr = qp + (size_t)q * HID_ + h * D_;
  float q0 = qptr[lane], q1 = qptr[lane + 64];

  float m = -1e30f, l = 0.f, acc0 = 0.f, acc1 = 0.f;
  for (int k = seg_start; k <= q; ++k) {
    const float* kptr = kp + (size_t)k * HID_ + h * D_;
    float s = q0 * kptr[lane] + q1 * kptr[lane + 64];
#pragma unroll
    for (int off = 32; off > 0; off >>= 1) s += __shfl_xor(s, off);
    s *= SCALE_;
    float mnew = fmaxf(m, s);
    float alpha = __expf(m - mnew);
    float p = __expf(s - mnew);
    const float* vptr = vp + (size_t)k * HID_ + h * D_;
    acc0 = acc0 * alpha + p * vptr[lane];
    acc1 = acc1 * alpha + p * vptr[lane + 64];
    l = l * alpha + p;
    m = mnew;
  }
  float inv = 1.f / l;
  attn[(size_t)q * HID_ + h * D_ + lane] = acc0 * inv;
  attn[(size_t)q * HID_ + h * D_ + lane + 64] = acc1 * inv;
}

// ---------------------------------------------------------------------------
// Paged decode attention. One wave per (batch, head). New K/V read from
// kp/vp (input caches are NOT mutated); loop runs over [0, kv_len] where
// position kv_len is the appended token.
// ---------------------------------------------------------------------------
__global__ __launch_bounds__(256) void attn_decode_kernel(
    const float* __restrict__ qp, const float* __restrict__ kp,
    const float* __restrict__ vp, const float* __restrict__ kcache,
    const float* __restrict__ vcache, const int* __restrict__ kv_lens,
    float* __restrict__ attn) {
  int b = blockIdx.y;
  int wave = threadIdx.x >> 6;
  int lane = threadIdx.x & 63;
  int h = blockIdx.x * 4 + wave;   // grid.x = H_/4
  int t = DOFF_ + b;

  const float* qptr = qp + (size_t)t * HID_ + h * D_;
  float q0 = qptr[lane], q1 = qptr[lane + 64];
  int len = kv_lens[b];

  float m = -1e30f, l = 0.f, acc0 = 0.f, acc1 = 0.f;
  for (int k = 0; k <= len; ++k) {
    const float* kptr;
    const float* vptr;
    if (k == len) {
      kptr = kp + (size_t)t * HID_ + h * D_;
      vptr = vp + (size_t)t * HID_ + h * D_;
    } else {
      size_t base = (((size_t)b * MAXKV_ + k) * H_ + h) * D_;
      kptr = kcache + base;
      vptr = vcache + base;
    }
    float s = q0 * kptr[lane] + q1 * kptr[lane + 64];
#pragma unroll
    for (int off = 32; off > 0; off >>= 1) s += __shfl_xor(s, off);
    s *= SCALE_;
    float mnew = fmaxf(m, s);
    float alpha = __expf(m - mnew);
    float p = __expf(s - mnew);
    acc0 = acc0 * alpha + p * vptr[lane];
    acc1 = acc1 * alpha + p * vptr[lane + 64];
    l = l * alpha + p;
    m = mnew;
  }
  float inv = 1.f / l;
  attn[(size_t)t * HID_ + h * D_ + lane] = acc0 * inv;
  attn[(size_t)t * HID_ + h * D_ + lane + 64] = acc1 * inv;
}

// ---------------------------------------------------------------------------
extern "C" void kernel_launch(void* const* d_in, const int* in_sizes, int n_in,
                              void* d_out, int out_size, void* d_ws, size_t ws_size,
                              hipStream_t stream) {
  const float* hidden  = (const float*)d_in[0];
  const float* Wq      = (const float*)d_in[1];
  const float* Wk      = (const float*)d_in[2];
  const float* Wv      = (const float*)d_in[3];
  const float* Wo      = (const float*)d_in[4];
  const float* wa_q    = (const float*)d_in[5];
  const float* wb_q    = (const float*)d_in[6];
  const float* wa_k    = (const float*)d_in[7];
  const float* wb_k    = (const float*)d_in[8];
  const float* wa_v    = (const float*)d_in[9];
  const float* wb_v    = (const float*)d_in[10];
  const float* wa_o    = (const float*)d_in[11];
  const float* wb_o    = (const float*)d_in[12];
  const float* k_cache = (const float*)d_in[13];
  const float* v_cache = (const float*)d_in[14];
  const int*   indptr  = (const int*)d_in[15];
  const int*   segment = (const int*)d_in[16];
  const int*   kv_lens = (const int*)d_in[17];
  float* out = (float*)d_out;

  float* ws = (float*)d_ws;
  const size_t PROJ = (size_t)T_ * HID_;
  float* qp   = ws;
  float* kp   = qp + PROJ;
  float* vp   = kp + PROJ;
  float* attn = vp + PROJ;
  float* u_q  = attn + PROJ;
  float* u_k  = u_q + (size_t)T_ * R_;
  float* u_v  = u_k + (size_t)T_ * R_;
  float* u_o  = u_v + (size_t)T_ * R_;

  // LoRA down-projections for q,k,v from hidden
  lora_u_kernel<<<T_, 256, 0, stream>>>(hidden, wa_q, segment, u_q);
  lora_u_kernel<<<T_, 256, 0, stream>>>(hidden, wa_k, segment, u_k);
  lora_u_kernel<<<T_, 256, 0, stream>>>(hidden, wa_v, segment, u_v);

  // QKV projections (+ fused LoRA up-proj)
  dim3 gg(HID_ / BN, (T_ + BM - 1) / BM);
  gemm_lora_kernel<<<gg, 256, 0, stream>>>(hidden, Wq, u_q, wb_q, segment, qp, T_);
  gemm_lora_kernel<<<gg, 256, 0, stream>>>(hidden, Wk, u_k, wb_k, segment, kp, T_);
  gemm_lora_kernel<<<gg, 256, 0, stream>>>(hidden, Wv, u_v, wb_v, segment, vp, T_);

  // attention
  attn_prefill_kernel<<<dim3(DOFF_ / 4, H_), 256, 0, stream>>>(qp, kp, vp, indptr, attn);
  attn_decode_kernel<<<dim3(H_ / 4, BD_), 256, 0, stream>>>(qp, kp, vp, k_cache, v_cache,
                                                            kv_lens, attn);

  // output projection (+ LoRA)
  lora_u_kernel<<<T_, 256, 0, stream>>>(attn, wa_o, segment, u_o);
  gemm_lora_kernel<<<gg, 256, 0, stream>>>(attn, Wo, u_o, wb_o, segment, out, T_);
}

// Round 2
// 991.233 us; speedup vs baseline: 3.0761x; 3.0761x over previous
//
#include <hip/hip_runtime.h>
#include <hip/hip_bf16.h>

#define H_     32
#define D_     128
#define HID_   4096
#define DOFF_  1024
#define BD_    32
#define T_     1056
#define MAXKV_ 513
#define R_     16
#define NA_    4
#define SCALE_ 0.08838834764831845f  /* 1/sqrt(128) */

typedef __attribute__((ext_vector_type(8))) short short8;
typedef __attribute__((ext_vector_type(4))) float f32x4;

__device__ __forceinline__ float toF(float x) { return x; }
__device__ __forceinline__ float toF(__hip_bfloat16 x) { return __bfloat162float(x); }
__device__ __forceinline__ void storev(float* p, float v) { *p = v; }
__device__ __forceinline__ void storev(__hip_bfloat16* p, float v) { *p = __float2bfloat16(v); }

__device__ __forceinline__ void gload16(const void* g, void* l) {
  __builtin_amdgcn_global_load_lds(
      (const __attribute__((address_space(1))) unsigned int*)g,
      (__attribute__((address_space(3))) unsigned int*)l, 16, 0, 0);
}

// ---------------------------------------------------------------------------
// fp32 -> bf16 elementwise cast (float4 / 4-wide)
// ---------------------------------------------------------------------------
__global__ __launch_bounds__(256) void cast_bf16_kernel(
    const float* __restrict__ X, __hip_bfloat16* __restrict__ Y, int n4) {
  int i = blockIdx.x * 256 + threadIdx.x;
  if (i >= n4) return;
  float4 v = ((const float4*)X)[i];
  __hip_bfloat16 o[4] = {__float2bfloat16(v.x), __float2bfloat16(v.y),
                         __float2bfloat16(v.z), __float2bfloat16(v.w)};
  *(short4*)(Y + (size_t)i * 4) = *(short4*)o;
}

// ---------------------------------------------------------------------------
// W[K][N] fp32 -> WT[N][K] bf16 (tiled transpose + cast)
// ---------------------------------------------------------------------------
__global__ __launch_bounds__(256) void transpose_cast_kernel(
    const float* __restrict__ W, __hip_bfloat16* __restrict__ WT) {
  __shared__ float tile[32][33];
  int tx = threadIdx.x & 31, ty = threadIdx.x >> 5;  // ty 0..7
  int r0 = blockIdx.y * 32, c0 = blockIdx.x * 32;
#pragma unroll
  for (int i = 0; i < 32; i += 8)
    tile[ty + i][tx] = W[(size_t)(r0 + ty + i) * HID_ + c0 + tx];
  __syncthreads();
#pragma unroll
  for (int i = 0; i < 32; i += 8)
    WT[(size_t)(c0 + ty + i) * HID_ + r0 + tx] = __float2bfloat16(tile[tx][ty + i]);
}

// ---------------------------------------------------------------------------
// u[t][r] = x[t] . WA[aid(t)][:,r]
// ---------------------------------------------------------------------------
template <typename XT>
__global__ __launch_bounds__(256) void lora_u_kernel(
    const XT* __restrict__ X, const float* __restrict__ WA,
    const int* __restrict__ segment, float* __restrict__ U) {
  int t = blockIdx.x;
  int tid = threadIdx.x;

  int aid = 0;
#pragma unroll
  for (int i = 1; i < NA_; ++i)
    if (t >= segment[i]) aid = i;

  const XT* x = X + (size_t)t * HID_;
  const float* wa = WA + (size_t)aid * HID_ * R_;

  float part[R_];
#pragma unroll
  for (int r = 0; r < R_; ++r) part[r] = 0.f;

  for (int h = tid; h < HID_; h += 256) {
    float xv = toF(x[h]);
    const float* w = wa + (size_t)h * R_;
#pragma unroll
    for (int r = 0; r < R_; ++r) part[r] += xv * w[r];
  }

  __shared__ float red[256][R_ + 1];
#pragma unroll
  for (int r = 0; r < R_; ++r) red[tid][r] = part[r];
  __syncthreads();
  for (int s = 128; s > 0; s >>= 1) {
    if (tid < s) {
#pragma unroll
      for (int r = 0; r < R_; ++r) red[tid][r] += red[tid + s][r];
    }
    __syncthreads();
  }
  if (tid < R_) U[(size_t)t * R_ + tid] = red[0][tid];
}

// ---------------------------------------------------------------------------
// Y[t][n] = Xb[t] . W[:,n] + sum_r U[t][r]*BMAT[aid(t)][r][n]
// bf16 MFMA, 128x128 tile, BK=32, 4 waves (2x2), global_load_lds staging.
// Xb: [Trows][HID] bf16 row-major. WT: [HID][HID] bf16 = W transposed (WT[n][k]).
// ---------------------------------------------------------------------------
template <typename OUT_T>
__global__ __launch_bounds__(256) void gemm_bf16_lora_kernel(
    const __hip_bfloat16* __restrict__ Xb, const __hip_bfloat16* __restrict__ WT,
    const float* __restrict__ U, const float* __restrict__ BMAT,
    const int* __restrict__ segment, OUT_T* __restrict__ Y, int Trows) {
  __shared__ __hip_bfloat16 As[128 * 32];
  __shared__ __hip_bfloat16 Bs[128 * 32];

  const int tid = threadIdx.x;
  const int lane = tid & 63;
  const int wave = tid >> 6;
  const int wr = (wave >> 1) * 64;   // wave row offset in tile
  const int wc = (wave & 1) * 64;    // wave col offset in tile
  const int m0 = blockIdx.y * 128, n0 = blockIdx.x * 128;

  // staging: 256 lanes x 16B = 4KB per issue; tile = 8KB -> 2 issues each
  const int srow = tid >> 2;          // 0..63
  const int sel = (tid & 3) * 8;      // element offset within 32-elem row
  int ar0 = m0 + srow;      if (ar0 >= Trows) ar0 = Trows - 1;
  int ar1 = m0 + srow + 64; if (ar1 >= Trows) ar1 = Trows - 1;
  const __hip_bfloat16* gA0 = Xb + (size_t)ar0 * HID_ + sel;
  const __hip_bfloat16* gA1 = Xb + (size_t)ar1 * HID_ + sel;
  const __hip_bfloat16* gB0 = WT + (size_t)(n0 + srow) * HID_ + sel;
  const __hip_bfloat16* gB1 = WT + (size_t)(n0 + srow + 64) * HID_ + sel;
  __hip_bfloat16* lA = As + tid * 8;   // linear: (row=tid/4)*32 + (tid%4)*8
  __hip_bfloat16* lB = Bs + tid * 8;

  const int lrow = lane & 15;
  const int lk = (lane >> 4) * 8;
  const __hip_bfloat16* fA = As + (wr + lrow) * 32 + lk;
  const __hip_bfloat16* fB = Bs + (wc + lrow) * 32 + lk;

  f32x4 acc[4][4] = {};

  for (int k0 = 0; k0 < HID_; k0 += 32) {
    gload16(gA0, lA);
    gload16(gA1, lA + 2048);
    gload16(gB0, lB);
    gload16(gB1, lB + 2048);
    gA0 += 32; gA1 += 32; gB0 += 32; gB1 += 32;
    __syncthreads();   // drains vmcnt(0): LDS tile ready
    short8 a[4], b[4];
#pragma unroll
    for (int mi = 0; mi < 4; ++mi) a[mi] = *(const short8*)(fA + mi * 512);
#pragma unroll
    for (int ni = 0; ni < 4; ++ni) b[ni] = *(const short8*)(fB + ni * 512);
#pragma unroll
    for (int mi = 0; mi < 4; ++mi)
#pragma unroll
      for (int ni = 0; ni < 4; ++ni)
        acc[mi][ni] = __builtin_amdgcn_mfma_f32_16x16x32_bf16(a[mi], b[ni], acc[mi][ni], 0, 0, 0);
    __syncthreads();   // all reads done before next staging overwrites
  }

  // epilogue: + segmented LoRA up-proj, store
  const int crow = (lane >> 4) * 4;
  const int ccol = lane & 15;
#pragma unroll
  for (int mi = 0; mi < 4; ++mi) {
    const int tb = m0 + wr + mi * 16 + crow;
#pragma unroll
    for (int i = 0; i < 4; ++i) {
      const int t = tb + i;
      if (t >= Trows) continue;
      int aid = 0;
#pragma unroll
      for (int s = 1; s < NA_; ++s)
        if (t >= segment[s]) aid = s;
      const float* ub = U + (size_t)t * R_;
      const float* bb = BMAT + (size_t)aid * R_ * HID_;
#pragma unroll
      for (int ni = 0; ni < 4; ++ni) {
        const int n = n0 + wc + ni * 16 + ccol;
        float v = acc[mi][ni][i];
        const float* bc = bb + n;
#pragma unroll
        for (int r = 0; r < R_; ++r) v += ub[r] * bc[(size_t)r * HID_];
        storev(Y + (size_t)t * HID_ + n, v);
      }
    }
  }
}

// ---------------------------------------------------------------------------
// Ragged causal prefill attention. Block = (q, h); 4 waves split the key
// range, online-softmax merge in LDS.
// ---------------------------------------------------------------------------
__global__ __launch_bounds__(256) void attn_prefill_kernel(
    const __hip_bfloat16* __restrict__ qp, const __hip_bfloat16* __restrict__ kp,
    const __hip_bfloat16* __restrict__ vp, const int* __restrict__ indptr,
    __hip_bfloat16* __restrict__ attn) {
  int q = blockIdx.x;
  int h = blockIdx.y;
  int wave = threadIdx.x >> 6;
  int lane = threadIdx.x & 63;

  int s0 = 0;
#pragma unroll
  for (int i = 1; i < NA_; ++i)
    if (q >= indptr[i]) s0 = indptr[i];

  const __hip_bfloat16* qptr = qp + (size_t)q * HID_ + h * D_;
  float q0 = toF(qptr[lane]), q1 = toF(qptr[lane + 64]);

  int n = q - s0 + 1;
  int chunk = (n + 3) >> 2;
  int ks = s0 + wave * chunk;
  int ke = ks + chunk; if (ke > q + 1) ke = q + 1;

  float m = -1e30f, l = 0.f, acc0 = 0.f, acc1 = 0.f;
  for (int k = ks; k < ke; ++k) {
    const __hip_bfloat16* kptr = kp + (size_t)k * HID_ + h * D_;
    float s = q0 * toF(kptr[lane]) + q1 * toF(kptr[lane + 64]);
#pragma unroll
    for (int off = 32; off > 0; off >>= 1) s += __shfl_xor(s, off);
    s *= SCALE_;
    float mnew = fmaxf(m, s);
    float alpha = __expf(m - mnew);
    float p = __expf(s - mnew);
    const __hip_bfloat16* vptr = vp + (size_t)k * HID_ + h * D_;
    acc0 = acc0 * alpha + p * toF(vptr[lane]);
    acc1 = acc1 * alpha + p * toF(vptr[lane + 64]);
    l = l * alpha + p;
    m = mnew;
  }

  __shared__ float sm[4], sl[4], sacc[4][128];
  if (lane == 0) { sm[wave] = m; sl[wave] = l; }
  sacc[wave][lane] = acc0;
  sacc[wave][lane + 64] = acc1;
  __syncthreads();
  if (wave == 0) {
    float M = fmaxf(fmaxf(sm[0], sm[1]), fmaxf(sm[2], sm[3]));
    float L = 0.f, A0 = 0.f, A1 = 0.f;
#pragma unroll
    for (int w = 0; w < 4; ++w) {
      float sc = __expf(sm[w] - M);
      L += sl[w] * sc;
      A0 += sacc[w][lane] * sc;
      A1 += sacc[w][lane + 64] * sc;
    }
    float inv = 1.f / L;
    __hip_bfloat16* outp = attn + (size_t)q * HID_ + h * D_;
    storev(outp + lane, A0 * inv);
    storev(outp + lane + 64, A1 * inv);
  }
}

// ---------------------------------------------------------------------------
// Paged decode attention. Block = (h, b); 4 waves split keys [0, len],
// position len is the appended token (read from kp/vp; caches not mutated).
// ---------------------------------------------------------------------------
__global__ __launch_bounds__(256) void attn_decode_kernel(
    const __hip_bfloat16* __restrict__ qp, const __hip_bfloat16* __restrict__ kp,
    const __hip_bfloat16* __restrict__ vp, const float* __restrict__ kcache,
    const float* __restrict__ vcache, const int* __restrict__ kv_lens,
    __hip_bfloat16* __restrict__ attn) {
  int h = blockIdx.x;
  int b = blockIdx.y;
  int wave = threadIdx.x >> 6;
  int lane = threadIdx.x & 63;
  int t = DOFF_ + b;

  const __hip_bfloat16* qptr = qp + (size_t)t * HID_ + h * D_;
  float q0 = toF(qptr[lane]), q1 = toF(qptr[lane + 64]);
  int len = kv_lens[b];

  int cnt = len + 1;
  int chunk = (cnt + 3) >> 2;
  int ks = wave * chunk;
  int ke = ks + chunk; if (ke > cnt) ke = cnt;

  float m = -1e30f, l = 0.f, acc0 = 0.f, acc1 = 0.f;
  for (int k = ks; k < ke; ++k) {
    float kv0, kv1, vv0, vv1;
    if (k == len) {
      const __hip_bfloat16* kptr = kp + (size_t)t * HID_ + h * D_;
      const __hip_bfloat16* vptr = vp + (size_t)t * HID_ + h * D_;
      kv0 = toF(kptr[lane]); kv1 = toF(kptr[lane + 64]);
      vv0 = toF(vptr[lane]); vv1 = toF(vptr[lane + 64]);
    } else {
      size_t base = (((size_t)b * MAXKV_ + k) * H_ + h) * D_;
      kv0 = kcache[base + lane]; kv1 = kcache[base + lane + 64];
      vv0 = vcache[base + lane]; vv1 = vcache[base + lane + 64];
    }
    float s = q0 * kv0 + q1 * kv1;
#pragma unroll
    for (int off = 32; off > 0; off >>= 1) s += __shfl_xor(s, off);
    s *= SCALE_;
    float mnew = fmaxf(m, s);
    float alpha = __expf(m - mnew);
    float p = __expf(s - mnew);
    acc0 = acc0 * alpha + p * vv0;
    acc1 = acc1 * alpha + p * vv1;
    l = l * alpha + p;
    m = mnew;
  }

  __shared__ float sm[4], sl[4], sacc[4][128];
  if (lane == 0) { sm[wave] = m; sl[wave] = l; }
  sacc[wave][lane] = acc0;
  sacc[wave][lane + 64] = acc1;
  __syncthreads();
  if (wave == 0) {
    float M = fmaxf(fmaxf(sm[0], sm[1]), fmaxf(sm[2], sm[3]));
    float L = 0.f, A0 = 0.f, A1 = 0.f;
#pragma unroll
    for (int w = 0; w < 4; ++w) {
      float sc = __expf(sm[w] - M);
      L += sl[w] * sc;
      A0 += sacc[w][lane] * sc;
      A1 += sacc[w][lane + 64] * sc;
    }
    float inv = 1.f / L;
    __hip_bfloat16* outp = attn + (size_t)t * HID_ + h * D_;
    storev(outp + lane, A0 * inv);
    storev(outp + lane + 64, A1 * inv);
  }
}

// ---------------------------------------------------------------------------
extern "C" void kernel_launch(void* const* d_in, const int* in_sizes, int n_in,
                              void* d_out, int out_size, void* d_ws, size_t ws_size,
                              hipStream_t stream) {
  const float* hidden  = (const float*)d_in[0];
  const float* Wq      = (const float*)d_in[1];
  const float* Wk      = (const float*)d_in[2];
  const float* Wv      = (const float*)d_in[3];
  const float* Wo      = (const float*)d_in[4];
  const float* wa_q    = (const float*)d_in[5];
  const float* wb_q    = (const float*)d_in[6];
  const float* wa_k    = (const float*)d_in[7];
  const float* wb_k    = (const float*)d_in[8];
  const float* wa_v    = (const float*)d_in[9];
  const float* wb_v    = (const float*)d_in[10];
  const float* wa_o    = (const float*)d_in[11];
  const float* wb_o    = (const float*)d_in[12];
  const float* k_cache = (const float*)d_in[13];
  const float* v_cache = (const float*)d_in[14];
  const int*   indptr  = (const int*)d_in[15];
  const int*   segment = (const int*)d_in[16];
  const int*   kv_lens = (const int*)d_in[17];
  float* out = (float*)d_out;

  const size_t PROJ = (size_t)T_ * HID_;
  __hip_bfloat16* Xb    = (__hip_bfloat16*)d_ws;
  __hip_bfloat16* qp    = Xb + PROJ;
  __hip_bfloat16* kp    = qp + PROJ;
  __hip_bfloat16* vp    = kp + PROJ;
  __hip_bfloat16* attnb = vp + PROJ;
  __hip_bfloat16* WT    = attnb + PROJ;                 // HID_*HID_ bf16
  float* u_q = (float*)(WT + (size_t)HID_ * HID_);
  float* u_k = u_q + (size_t)T_ * R_;
  float* u_v = u_k + (size_t)T_ * R_;
  float* u_o = u_v + (size_t)T_ * R_;

  const int n4 = (int)(PROJ / 4);
  dim3 tg(HID_ / 32, HID_ / 32);
  dim3 gg(HID_ / 128, (T_ + 127) / 128);

  cast_bf16_kernel<<<(n4 + 255) / 256, 256, 0, stream>>>(hidden, Xb, n4);
  lora_u_kernel<float><<<T_, 256, 0, stream>>>(hidden, wa_q, segment, u_q);
  lora_u_kernel<float><<<T_, 256, 0, stream>>>(hidden, wa_k, segment, u_k);
  lora_u_kernel<float><<<T_, 256, 0, stream>>>(hidden, wa_v, segment, u_v);

  transpose_cast_kernel<<<tg, 256, 0, stream>>>(Wq, WT);
  gemm_bf16_lora_kernel<__hip_bfloat16><<<gg, 256, 0, stream>>>(Xb, WT, u_q, wb_q, segment, qp, T_);
  transpose_cast_kernel<<<tg, 256, 0, stream>>>(Wk, WT);
  gemm_bf16_lora_kernel<__hip_bfloat16><<<gg, 256, 0, stream>>>(Xb, WT, u_k, wb_k, segment, kp, T_);
  transpose_cast_kernel<<<tg, 256, 0, stream>>>(Wv, WT);
  gemm_bf16_lora_kernel<__hip_bfloat16><<<gg, 256, 0, stream>>>(Xb, WT, u_v, wb_v, segment, vp, T_);

  attn_prefill_kernel<<<dim3(DOFF_, H_), 256, 0, stream>>>(qp, kp, vp, indptr, attnb);
  attn_decode_kernel<<<dim3(H_, BD_), 256, 0, stream>>>(qp, kp, vp, k_cache, v_cache,
                                                        kv_lens, attnb);

  lora_u_kernel<__hip_bfloat16><<<T_, 256, 0, stream>>>(attnb, wa_o, segment, u_o);
  transpose_cast_kernel<<<tg, 256, 0, stream>>>(Wo, WT);
  gemm_bf16_lora_kernel<float><<<gg, 256, 0, stream>>>(attnb, WT, u_o, wb_o, segment, out, T_);
}

// Round 3
// 723.068 us; speedup vs baseline: 4.2170x; 1.3709x over previous
//
#include <hip/hip_runtime.h>
#include <hip/hip_bf16.h>

#define H_     32
#define D_     128
#define HID_   4096
#define DOFF_  1024
#define BD_    32
#define T_     1056
#define MAXKV_ 513
#define R_     16
#define NA_    4
#define SCALE_ 0.08838834764831845f  /* 1/sqrt(128) */

typedef __attribute__((ext_vector_type(8))) short short8;
typedef __attribute__((ext_vector_type(4))) float f32x4;

__device__ __forceinline__ float toF(float x) { return x; }
__device__ __forceinline__ float toF(__hip_bfloat16 x) { return __bfloat162float(x); }
__device__ __forceinline__ void storev(float* p, float v) { *p = v; }
__device__ __forceinline__ void storev(__hip_bfloat16* p, float v) { *p = __float2bfloat16(v); }

__device__ __forceinline__ void gload16(const void* g, void* l) {
  __builtin_amdgcn_global_load_lds(
      (const __attribute__((address_space(1))) unsigned int*)g,
      (__attribute__((address_space(3))) unsigned int*)l, 16, 0, 0);
}

// ---------------------------------------------------------------------------
// fp32 -> bf16 elementwise cast
// ---------------------------------------------------------------------------
__global__ __launch_bounds__(256) void cast_bf16_kernel(
    const float* __restrict__ X, __hip_bfloat16* __restrict__ Y, int n4) {
  int i = blockIdx.x * 256 + threadIdx.x;
  if (i >= n4) return;
  float4 v = ((const float4*)X)[i];
  __hip_bfloat16 o[4] = {__float2bfloat16(v.x), __float2bfloat16(v.y),
                         __float2bfloat16(v.z), __float2bfloat16(v.w)};
  *(short4*)(Y + (size_t)i * 4) = *(short4*)o;
}

// ---------------------------------------------------------------------------
// W[K][N] fp32 -> WT[N][K] bf16 (tiled transpose + cast)
// ---------------------------------------------------------------------------
__global__ __launch_bounds__(256) void transpose_cast_kernel(
    const float* __restrict__ W, __hip_bfloat16* __restrict__ WT) {
  __shared__ float tile[32][33];
  int tx = threadIdx.x & 31, ty = threadIdx.x >> 5;  // ty 0..7
  int r0 = blockIdx.y * 32, c0 = blockIdx.x * 32;
#pragma unroll
  for (int i = 0; i < 32; i += 8)
    tile[ty + i][tx] = W[(size_t)(r0 + ty + i) * HID_ + c0 + tx];
  __syncthreads();
#pragma unroll
  for (int i = 0; i < 32; i += 8)
    WT[(size_t)(c0 + ty + i) * HID_ + r0 + tx] = __float2bfloat16(tile[tx][ty + i]);
}

// ---------------------------------------------------------------------------
// u[t][r] = x[t] . WA[aid(t)][:,r]
// ---------------------------------------------------------------------------
template <typename XT>
__global__ __launch_bounds__(256) void lora_u_kernel(
    const XT* __restrict__ X, const float* __restrict__ WA,
    const int* __restrict__ segment, float* __restrict__ U) {
  int t = blockIdx.x;
  int tid = threadIdx.x;

  int aid = 0;
#pragma unroll
  for (int i = 1; i < NA_; ++i)
    if (t >= segment[i]) aid = i;

  const XT* x = X + (size_t)t * HID_;
  const float* wa = WA + (size_t)aid * HID_ * R_;

  float part[R_];
#pragma unroll
  for (int r = 0; r < R_; ++r) part[r] = 0.f;

  for (int h = tid; h < HID_; h += 256) {
    float xv = toF(x[h]);
    const float* w = wa + (size_t)h * R_;
#pragma unroll
    for (int r = 0; r < R_; ++r) part[r] += xv * w[r];
  }

  __shared__ float red[256][R_ + 1];
#pragma unroll
  for (int r = 0; r < R_; ++r) red[tid][r] = part[r];
  __syncthreads();
  for (int s = 128; s > 0; s >>= 1) {
    if (tid < s) {
#pragma unroll
      for (int r = 0; r < R_; ++r) red[tid][r] += red[tid + s][r];
    }
    __syncthreads();
  }
  if (tid < R_) U[(size_t)t * R_ + tid] = red[0][tid];
}

// ---------------------------------------------------------------------------
// GEMM: Y[t][n] = Xb[t].W[:,n] + LoRA.  bf16 MFMA, 128x128 tile, BK=32.
// ---------------------------------------------------------------------------
template <typename OUT_T>
__global__ __launch_bounds__(256) void gemm_bf16_lora_kernel(
    const __hip_bfloat16* __restrict__ Xb, const __hip_bfloat16* __restrict__ WT,
    const float* __restrict__ U, const float* __restrict__ BMAT,
    const int* __restrict__ segment, OUT_T* __restrict__ Y, int Trows) {
  __shared__ __hip_bfloat16 As[128 * 32];
  __shared__ __hip_bfloat16 Bs[128 * 32];

  const int tid = threadIdx.x;
  const int lane = tid & 63;
  const int wave = tid >> 6;
  const int wr = (wave >> 1) * 64;
  const int wc = (wave & 1) * 64;
  const int m0 = blockIdx.y * 128, n0 = blockIdx.x * 128;

  const int srow = tid >> 2;
  const int sel = (tid & 3) * 8;
  int ar0 = m0 + srow;      if (ar0 >= Trows) ar0 = Trows - 1;
  int ar1 = m0 + srow + 64; if (ar1 >= Trows) ar1 = Trows - 1;
  const __hip_bfloat16* gA0 = Xb + (size_t)ar0 * HID_ + sel;
  const __hip_bfloat16* gA1 = Xb + (size_t)ar1 * HID_ + sel;
  const __hip_bfloat16* gB0 = WT + (size_t)(n0 + srow) * HID_ + sel;
  const __hip_bfloat16* gB1 = WT + (size_t)(n0 + srow + 64) * HID_ + sel;
  __hip_bfloat16* lA = As + tid * 8;
  __hip_bfloat16* lB = Bs + tid * 8;

  const int lrow = lane & 15;
  const int lk = (lane >> 4) * 8;
  const __hip_bfloat16* fA = As + (wr + lrow) * 32 + lk;
  const __hip_bfloat16* fB = Bs + (wc + lrow) * 32 + lk;

  f32x4 acc[4][4] = {};

  for (int k0 = 0; k0 < HID_; k0 += 32) {
    gload16(gA0, lA);
    gload16(gA1, lA + 2048);
    gload16(gB0, lB);
    gload16(gB1, lB + 2048);
    gA0 += 32; gA1 += 32; gB0 += 32; gB1 += 32;
    __syncthreads();
    short8 a[4], b[4];
#pragma unroll
    for (int mi = 0; mi < 4; ++mi) a[mi] = *(const short8*)(fA + mi * 512);
#pragma unroll
    for (int ni = 0; ni < 4; ++ni) b[ni] = *(const short8*)(fB + ni * 512);
#pragma unroll
    for (int mi = 0; mi < 4; ++mi)
#pragma unroll
      for (int ni = 0; ni < 4; ++ni)
        acc[mi][ni] = __builtin_amdgcn_mfma_f32_16x16x32_bf16(a[mi], b[ni], acc[mi][ni], 0, 0, 0);
    __syncthreads();
  }

  const int crow = (lane >> 4) * 4;
  const int ccol = lane & 15;
#pragma unroll
  for (int mi = 0; mi < 4; ++mi) {
    const int tb = m0 + wr + mi * 16 + crow;
#pragma unroll
    for (int i = 0; i < 4; ++i) {
      const int t = tb + i;
      if (t >= Trows) continue;
      int aid = 0;
#pragma unroll
      for (int s = 1; s < NA_; ++s)
        if (t >= segment[s]) aid = s;
      const float* ub = U + (size_t)t * R_;
      const float* bb = BMAT + (size_t)aid * R_ * HID_;
#pragma unroll
      for (int ni = 0; ni < 4; ++ni) {
        const int n = n0 + wc + ni * 16 + ccol;
        float v = acc[mi][ni][i];
        const float* bc = bb + n;
#pragma unroll
        for (int r = 0; r < R_; ++r) v += ub[r] * bc[(size_t)r * HID_];
        storev(Y + (size_t)t * HID_ + n, v);
      }
    }
  }
}

// ---------------------------------------------------------------------------
// MFMA flash prefill. Block = 64 queries x 1 head, 4 waves x 16 q-rows.
// K staged swizzled via global_load_lds; V staged transposed (Vt[d][k]).
// ---------------------------------------------------------------------------
#define QB 64
#define KB 32

__global__ __launch_bounds__(256) void attn_prefill_mfma_kernel(
    const __hip_bfloat16* __restrict__ qp, const __hip_bfloat16* __restrict__ kp,
    const __hip_bfloat16* __restrict__ vp, const int* __restrict__ indptr,
    __hip_bfloat16* __restrict__ attn) {
  __shared__ __hip_bfloat16 Klds[KB * 128];     // XOR-swizzled (chunk ^= row&7)
  __shared__ __hip_bfloat16 Vt[128 * 40];       // Vt[d][k], rows padded to 40
  __shared__ __hip_bfloat16 Plds[4][16 * 40];   // per-wave P, rows padded to 40

  const int tid = threadIdx.x;
  const int lane = tid & 63;
  const int wave = tid >> 6;
  const int g = lane >> 4;
  const int lc = lane & 15;
  const int q0 = blockIdx.x * QB;
  const int h = blockIdx.y;

  int qrows[4], qstart[4];
#pragma unroll
  for (int i = 0; i < 4; ++i) {
    int q = q0 + wave * 16 + g * 4 + i;
    qrows[i] = q;
    int s0 = 0;
#pragma unroll
    for (int j = 1; j < NA_; ++j)
      if (q >= indptr[j]) s0 = indptr[j];
    qstart[i] = s0;
  }

  // Q a-frags: row = lc, k-elems = dc*32 + g*8 + [0..7]
  short8 aq[4];
  {
    const __hip_bfloat16* qrow = qp + (size_t)(q0 + wave * 16 + lc) * HID_ + h * D_;
#pragma unroll
    for (int dc = 0; dc < 4; ++dc)
      aq[dc] = *(const short8*)(qrow + dc * 32 + g * 8);
  }

  float mrow[4], lrow[4];
#pragma unroll
  for (int i = 0; i < 4; ++i) { mrow[i] = -1e30f; lrow[i] = 0.f; }
  f32x4 o[8] = {};

  int ks0 = 0;
#pragma unroll
  for (int j = 1; j < NA_; ++j)
    if (q0 >= indptr[j]) ks0 = indptr[j];
  const int kt0 = ks0 & ~(KB - 1);

  const int sr = tid >> 4;   // 0..15
  const int sc = tid & 15;   // 16B chunk 0..15

  for (int kt = kt0; kt < q0 + QB; kt += KB) {
    // K: swizzled source -> linear LDS (involution: read applies same XOR)
    gload16(kp + (size_t)(kt + sr) * HID_ + h * D_ + ((sc ^ (sr & 7)) * 8),
            Klds + tid * 8);
    gload16(kp + (size_t)(kt + 16 + sr) * HID_ + h * D_ + ((sc ^ (sr & 7)) * 8),
            Klds + 2048 + tid * 8);
    // V: reg-stage, write transposed
    {
      short8 v0 = *(const short8*)(vp + (size_t)(kt + sr) * HID_ + h * D_ + sc * 8);
      short8 v1 = *(const short8*)(vp + (size_t)(kt + 16 + sr) * HID_ + h * D_ + sc * 8);
      const __hip_bfloat16* e0 = (const __hip_bfloat16*)&v0;
      const __hip_bfloat16* e1 = (const __hip_bfloat16*)&v1;
#pragma unroll
      for (int e = 0; e < 8; ++e) {
        Vt[(sc * 8 + e) * 40 + sr] = e0[e];
        Vt[(sc * 8 + e) * 40 + sr + 16] = e1[e];
      }
    }
    __syncthreads();

    // QK^T: two 16x16 S-tiles (cols kt..kt+15, kt+16..kt+31)
    f32x4 s0v = {}, s1v = {};
#pragma unroll
    for (int dc = 0; dc < 4; ++dc) {
      const int cb = dc * 4 + g;
      short8 bk0 = *(const short8*)(Klds + lc * 128 + ((cb ^ (lc & 7)) * 8));
      short8 bk1 = *(const short8*)(Klds + (16 + lc) * 128 + ((cb ^ (lc & 7)) * 8));
      s0v = __builtin_amdgcn_mfma_f32_16x16x32_bf16(aq[dc], bk0, s0v, 0, 0, 0);
      s1v = __builtin_amdgcn_mfma_f32_16x16x32_bf16(aq[dc], bk1, s1v, 0, 0, 0);
    }

    const int kl0 = kt + lc, kl1 = kt + 16 + lc;
#pragma unroll
    for (int i = 0; i < 4; ++i) {
      float sm0 = s0v[i] * SCALE_;
      float sm1 = s1v[i] * SCALE_;
      bool v0ok = (kl0 >= qstart[i]) && (kl0 <= qrows[i]);
      bool v1ok = (kl1 >= qstart[i]) && (kl1 <= qrows[i]);
      float mx = fmaxf(v0ok ? sm0 : -1e30f, v1ok ? sm1 : -1e30f);
#pragma unroll
      for (int off = 1; off < 16; off <<= 1)
        mx = fmaxf(mx, __shfl_xor(mx, off));
      float mnew = fmaxf(mrow[i], mx);
      float alpha = __expf(mrow[i] - mnew);
      float p0 = v0ok ? __expf(sm0 - mnew) : 0.f;
      float p1 = v1ok ? __expf(sm1 - mnew) : 0.f;
      lrow[i] = lrow[i] * alpha + p0 + p1;
      mrow[i] = mnew;
#pragma unroll
      for (int dc = 0; dc < 8; ++dc) o[dc][i] *= alpha;
      Plds[wave][(g * 4 + i) * 40 + lc] = __float2bfloat16(p0);
      Plds[wave][(g * 4 + i) * 40 + 16 + lc] = __float2bfloat16(p1);
    }

    asm volatile("s_waitcnt lgkmcnt(0)" ::: "memory");

    // PV: A = P (row=lc, k=g*8..), B = Vt columns
    short8 ap = *(const short8*)(&Plds[wave][lc * 40 + g * 8]);
#pragma unroll
    for (int dc = 0; dc < 8; ++dc) {
      short8 bv = *(const short8*)(&Vt[(dc * 16 + lc) * 40 + g * 8]);
      o[dc] = __builtin_amdgcn_mfma_f32_16x16x32_bf16(ap, bv, o[dc], 0, 0, 0);
    }
    __syncthreads();
  }

  // epilogue: reduce l across the 16-lane group, normalize, store
#pragma unroll
  for (int i = 0; i < 4; ++i) {
    float l = lrow[i];
#pragma unroll
    for (int off = 1; off < 16; off <<= 1) l += __shfl_xor(l, off);
    lrow[i] = 1.f / l;
  }
#pragma unroll
  for (int dc = 0; dc < 8; ++dc)
#pragma unroll
    for (int i = 0; i < 4; ++i)
      attn[(size_t)qrows[i] * HID_ + h * D_ + dc * 16 + lc] =
          __float2bfloat16(o[dc][i] * lrow[i]);
}

// ---------------------------------------------------------------------------
// Paged decode attention (4 waves split keys; appended token from kp/vp).
// ---------------------------------------------------------------------------
__global__ __launch_bounds__(256) void attn_decode_kernel(
    const __hip_bfloat16* __restrict__ qp, const __hip_bfloat16* __restrict__ kp,
    const __hip_bfloat16* __restrict__ vp, const float* __restrict__ kcache,
    const float* __restrict__ vcache, const int* __restrict__ kv_lens,
    __hip_bfloat16* __restrict__ attn) {
  int h = blockIdx.x;
  int b = blockIdx.y;
  int wave = threadIdx.x >> 6;
  int lane = threadIdx.x & 63;
  int t = DOFF_ + b;

  const __hip_bfloat16* qptr = qp + (size_t)t * HID_ + h * D_;
  float q0 = toF(qptr[lane]), q1 = toF(qptr[lane + 64]);
  int len = kv_lens[b];

  int cnt = len + 1;
  int chunk = (cnt + 3) >> 2;
  int ks = wave * chunk;
  int ke = ks + chunk; if (ke > cnt) ke = cnt;

  float m = -1e30f, l = 0.f, acc0 = 0.f, acc1 = 0.f;
  for (int k = ks; k < ke; ++k) {
    float kv0, kv1, vv0, vv1;
    if (k == len) {
      const __hip_bfloat16* kptr = kp + (size_t)t * HID_ + h * D_;
      const __hip_bfloat16* vptr = vp + (size_t)t * HID_ + h * D_;
      kv0 = toF(kptr[lane]); kv1 = toF(kptr[lane + 64]);
      vv0 = toF(vptr[lane]); vv1 = toF(vptr[lane + 64]);
    } else {
      size_t base = (((size_t)b * MAXKV_ + k) * H_ + h) * D_;
      kv0 = kcache[base + lane]; kv1 = kcache[base + lane + 64];
      vv0 = vcache[base + lane]; vv1 = vcache[base + lane + 64];
    }
    float s = q0 * kv0 + q1 * kv1;
#pragma unroll
    for (int off = 32; off > 0; off >>= 1) s += __shfl_xor(s, off);
    s *= SCALE_;
    float mnew = fmaxf(m, s);
    float alpha = __expf(m - mnew);
    float p = __expf(s - mnew);
    acc0 = acc0 * alpha + p * vv0;
    acc1 = acc1 * alpha + p * vv1;
    l = l * alpha + p;
    m = mnew;
  }

  __shared__ float sm[4], sl[4], sacc[4][128];
  if (lane == 0) { sm[wave] = m; sl[wave] = l; }
  sacc[wave][lane] = acc0;
  sacc[wave][lane + 64] = acc1;
  __syncthreads();
  if (wave == 0) {
    float M = fmaxf(fmaxf(sm[0], sm[1]), fmaxf(sm[2], sm[3]));
    float L = 0.f, A0 = 0.f, A1 = 0.f;
#pragma unroll
    for (int w = 0; w < 4; ++w) {
      float sc = __expf(sm[w] - M);
      L += sl[w] * sc;
      A0 += sacc[w][lane] * sc;
      A1 += sacc[w][lane + 64] * sc;
    }
    float inv = 1.f / L;
    __hip_bfloat16* outp = attn + (size_t)t * HID_ + h * D_;
    storev(outp + lane, A0 * inv);
    storev(outp + lane + 64, A1 * inv);
  }
}

// ---------------------------------------------------------------------------
extern "C" void kernel_launch(void* const* d_in, const int* in_sizes, int n_in,
                              void* d_out, int out_size, void* d_ws, size_t ws_size,
                              hipStream_t stream) {
  const float* hidden  = (const float*)d_in[0];
  const float* Wq      = (const float*)d_in[1];
  const float* Wk      = (const float*)d_in[2];
  const float* Wv      = (const float*)d_in[3];
  const float* Wo      = (const float*)d_in[4];
  const float* wa_q    = (const float*)d_in[5];
  const float* wb_q    = (const float*)d_in[6];
  const float* wa_k    = (const float*)d_in[7];
  const float* wb_k    = (const float*)d_in[8];
  const float* wa_v    = (const float*)d_in[9];
  const float* wb_v    = (const float*)d_in[10];
  const float* wa_o    = (const float*)d_in[11];
  const float* wb_o    = (const float*)d_in[12];
  const float* k_cache = (const float*)d_in[13];
  const float* v_cache = (const float*)d_in[14];
  const int*   indptr  = (const int*)d_in[15];
  const int*   segment = (const int*)d_in[16];
  const int*   kv_lens = (const int*)d_in[17];
  float* out = (float*)d_out;

  const size_t PROJ = (size_t)T_ * HID_;
  __hip_bfloat16* Xb    = (__hip_bfloat16*)d_ws;
  __hip_bfloat16* qp    = Xb + PROJ;
  __hip_bfloat16* kp    = qp + PROJ;
  __hip_bfloat16* vp    = kp + PROJ;
  __hip_bfloat16* attnb = vp + PROJ;
  __hip_bfloat16* WT    = attnb + PROJ;                 // HID_*HID_ bf16
  float* u_q = (float*)(WT + (size_t)HID_ * HID_);
  float* u_k = u_q + (size_t)T_ * R_;
  float* u_v = u_k + (size_t)T_ * R_;
  float* u_o = u_v + (size_t)T_ * R_;

  const int n4 = (int)(PROJ / 4);
  dim3 tg(HID_ / 32, HID_ / 32);
  dim3 gg(HID_ / 128, (T_ + 127) / 128);

  cast_bf16_kernel<<<(n4 + 255) / 256, 256, 0, stream>>>(hidden, Xb, n4);
  lora_u_kernel<float><<<T_, 256, 0, stream>>>(hidden, wa_q, segment, u_q);
  lora_u_kernel<float><<<T_, 256, 0, stream>>>(hidden, wa_k, segment, u_k);
  lora_u_kernel<float><<<T_, 256, 0, stream>>>(hidden, wa_v, segment, u_v);

  transpose_cast_kernel<<<tg, 256, 0, stream>>>(Wq, WT);
  gemm_bf16_lora_kernel<__hip_bfloat16><<<gg, 256, 0, stream>>>(Xb, WT, u_q, wb_q, segment, qp, T_);
  transpose_cast_kernel<<<tg, 256, 0, stream>>>(Wk, WT);
  gemm_bf16_lora_kernel<__hip_bfloat16><<<gg, 256, 0, stream>>>(Xb, WT, u_k, wb_k, segment, kp, T_);
  transpose_cast_kernel<<<tg, 256, 0, stream>>>(Wv, WT);
  gemm_bf16_lora_kernel<__hip_bfloat16><<<gg, 256, 0, stream>>>(Xb, WT, u_v, wb_v, segment, vp, T_);

  attn_prefill_mfma_kernel<<<dim3(DOFF_ / QB, H_), 256, 0, stream>>>(qp, kp, vp, indptr, attnb);
  attn_decode_kernel<<<dim3(H_, BD_), 256, 0, stream>>>(qp, kp, vp, k_cache, v_cache,
                                                        kv_lens, attnb);

  lora_u_kernel<__hip_bfloat16><<<T_, 256, 0, stream>>>(attnb, wa_o, segment, u_o);
  transpose_cast_kernel<<<tg, 256, 0, stream>>>(Wo, WT);
  gemm_bf16_lora_kernel<float><<<gg, 256, 0, stream>>>(attnb, WT, u_o, wb_o, segment, out, T_);
}